// Round 1
// baseline (38.814 us; speedup 1.0000x reference)
//
#include <hip/hip_runtime.h>

#define NSTEP 32
// DIM = 2+4+8+16+32 = 62 monomials of degree 1..5 over (x0,x1)

// ---------------------------------------------------------------------------
// Prep: collapse each 62-float weight vector into 30 gradient coefficients.
//   canonical c[a][b] = sum of w over all multi-indices with a zeros / b ones
//   dP/dx0 coeffs G0[e0][e1] = (e0+1)*c[e0+1][e1], rows by e0 (for Horner in x1)
//   dP/dx1 coeffs G1[e1][e0] = (e1+1)*c[e0][e1+1], rows by e1 (for Horner in x0)
// Output layout: G[(step*4+which)*32 + k], k=0..14 -> G0 (triangular row-major),
// k=15..29 -> G1, k=30..31 pad.
// ---------------------------------------------------------------------------
__global__ void prep_kernel(const float* __restrict__ Aw, const float* __restrict__ Bw,
                            const float* __restrict__ Cw, const float* __restrict__ Dw,
                            float* __restrict__ G) {
    int t = blockIdx.x * blockDim.x + threadIdx.x;
    if (t >= NSTEP * 4) return;
    int stepi = t >> 2, which = t & 3;
    const float* w;
    switch (which) { case 0: w = Aw; break; case 1: w = Bw; break;
                     case 2: w = Cw; break; default: w = Dw; }
    w += stepi * 62;

    float c[6][6];
#pragma unroll
    for (int a = 0; a < 6; ++a)
#pragma unroll
        for (int b = 0; b < 6; ++b) c[a][b] = 0.f;

    // degree-d flat index f: bits of f (d bits) are the indices; popcount = power of x1
#pragma unroll
    for (int d = 1; d <= 5; ++d) {
#pragma unroll
        for (int f = 0; f < (1 << d); ++f) {
            int b = __popc(f);
            c[d - b][b] += w[(1 << d) - 2 + f];
        }
    }

    float out[32];
#pragma unroll
    for (int i = 0; i < 32; ++i) out[i] = 0.f;
    int k = 0;
#pragma unroll
    for (int e0 = 0; e0 <= 4; ++e0)
#pragma unroll
        for (int e1 = 0; e1 + e0 <= 4; ++e1)
            out[k++] = (float)(e0 + 1) * c[e0 + 1][e1];
#pragma unroll
    for (int e1 = 0; e1 <= 4; ++e1)
#pragma unroll
        for (int e0 = 0; e0 + e1 <= 4; ++e0)
            out[k++] = (float)(e1 + 1) * c[e0][e1 + 1];

    float* dst = G + t * 32;
#pragma unroll
    for (int i = 0; i < 32; ++i) dst[i] = out[i];
}

// ---------------------------------------------------------------------------
// Gradient of the degree-5 poly: two bivariate degree-4 Horner evaluations.
// g[0..14] rows by e0 (inner Horner in x1), g[15..29] rows by e1 (inner in x0).
// Row starts (triangular, widths 5,4,3,2,1): 0,5,9,12,14.
// ---------------------------------------------------------------------------
__device__ __forceinline__ void pgrad(const float* __restrict__ g, float x0, float x1,
                                      float& d0, float& d1) {
    float r0 = fmaf(fmaf(fmaf(fmaf(g[4], x1, g[3]), x1, g[2]), x1, g[1]), x1, g[0]);
    float r1 = fmaf(fmaf(fmaf(g[8], x1, g[7]), x1, g[6]), x1, g[5]);
    float r2 = fmaf(fmaf(g[11], x1, g[10]), x1, g[9]);
    float r3 = fmaf(g[13], x1, g[12]);
    float r4 = g[14];
    d0 = fmaf(fmaf(fmaf(fmaf(r4, x0, r3), x0, r2), x0, r1), x0, r0);

    float s0 = fmaf(fmaf(fmaf(fmaf(g[19], x0, g[18]), x0, g[17]), x0, g[16]), x0, g[15]);
    float s1 = fmaf(fmaf(fmaf(g[23], x0, g[22]), x0, g[21]), x0, g[20]);
    float s2 = fmaf(fmaf(g[26], x0, g[25]), x0, g[24]);
    float s3 = fmaf(g[28], x0, g[27]);
    float s4 = g[29];
    d1 = fmaf(fmaf(fmaf(fmaf(s4, x1, s3), x1, s2), x1, s1), x1, s0);
}

__global__ void __launch_bounds__(256) sympl_kernel(const float* __restrict__ zin,
                                                    const float* __restrict__ G,
                                                    const int* __restrict__ nsp,
                                                    float* __restrict__ zout, int batch) {
    int idx = blockIdx.x * blockDim.x + threadIdx.x;
    if (idx >= batch) return;
    float dt  = 1.0f / (32.0f * (float)(*nsp));
    float hdt = 0.5f * dt;

    float4 z = reinterpret_cast<const float4*>(zin)[idx];
    float q0 = z.x, q1 = z.y, p0 = z.z, p1 = z.w;

    for (int s = 0; s < NSTEP; ++s) {
        const float* gS = G + s * 128;   // uniform per-wave -> scalar loads

        float dA0, dA1; pgrad(gS, p0, p1, dA0, dA1);
        q0 = fmaf(dA0, hdt, q0); q1 = fmaf(dA1, hdt, q1);

        float dB0, dB1; pgrad(gS + 32, q0, q1, dB0, dB1);
        p0 = fmaf(-dB0, dt, p0); p1 = fmaf(-dB1, dt, p1);

        q0 = fmaf(dA0, hdt, q0); q1 = fmaf(dA1, hdt, q1);

        float u0 = q1, u1 = p0, v0 = q0, v1 = p1;

        float dC0, dC1; pgrad(gS + 64, v0, v1, dC0, dC1);
        u0 = fmaf(dC1, hdt, u0); u1 = fmaf(-dC0, hdt, u1);

        float dD0, dD1; pgrad(gS + 96, u0, u1, dD0, dD1);
        v0 = fmaf(dD1, dt, v0); v1 = fmaf(-dD0, dt, v1);

        u0 = fmaf(dC1, hdt, u0); u1 = fmaf(-dC0, hdt, u1);

        q0 = v0; q1 = u0; p0 = u1; p1 = v1;  // z = [v0, u0, u1, v1]
    }

    float4 o; o.x = q0; o.y = q1; o.z = p0; o.w = p1;
    reinterpret_cast<float4*>(zout)[idx] = o;
}

extern "C" void kernel_launch(void* const* d_in, const int* in_sizes, int n_in,
                              void* d_out, int out_size, void* d_ws, size_t ws_size,
                              hipStream_t stream) {
    const float* z  = (const float*)d_in[0];
    const float* Aw = (const float*)d_in[1];
    const float* Bw = (const float*)d_in[2];
    const float* Cw = (const float*)d_in[3];
    const float* Dw = (const float*)d_in[4];
    const int*   ns = (const int*)d_in[5];
    float* G = (float*)d_ws;   // 32*4*32 floats = 16 KB

    prep_kernel<<<1, 128, 0, stream>>>(Aw, Bw, Cw, Dw, G);

    int batch = in_sizes[0] / 4;
    int threads = 256;
    int blocks = (batch + threads - 1) / threads;
    sympl_kernel<<<blocks, threads, 0, stream>>>(z, G, ns, (float*)d_out, batch);
}

// Round 2
// 20.792 us; speedup vs baseline: 1.8668x; 1.8668x over previous
//
#include <hip/hip_runtime.h>

#define NSTEP 32
// DIM = 62 monomials of degree 1..5 over (x0,x1); collapsed to 30 gradient
// coefficients per (step, stage). LDS layout: sG[step*128 + stage*32 + k],
// k=0..14 -> dP/dx0 coeffs (triangular rows by e0, inner Horner in x1),
// k=15..29 -> dP/dx1 coeffs (rows by e1, inner Horner in x0), 30..31 pad.

__device__ __forceinline__ void loadstage(const float* __restrict__ sg, float (&g)[32]) {
#pragma unroll
    for (int i = 0; i < 8; ++i) {
        float4 v = *reinterpret_cast<const float4*>(sg + i * 4);
        g[i * 4 + 0] = v.x; g[i * 4 + 1] = v.y;
        g[i * 4 + 2] = v.z; g[i * 4 + 3] = v.w;
    }
}

__device__ __forceinline__ void pgrad(const float (&g)[32], float x0, float x1,
                                      float& d0, float& d1) {
    float r0 = fmaf(fmaf(fmaf(fmaf(g[4], x1, g[3]), x1, g[2]), x1, g[1]), x1, g[0]);
    float r1 = fmaf(fmaf(fmaf(g[8], x1, g[7]), x1, g[6]), x1, g[5]);
    float r2 = fmaf(fmaf(g[11], x1, g[10]), x1, g[9]);
    float r3 = fmaf(g[13], x1, g[12]);
    float r4 = g[14];
    d0 = fmaf(fmaf(fmaf(fmaf(r4, x0, r3), x0, r2), x0, r1), x0, r0);

    float s0 = fmaf(fmaf(fmaf(fmaf(g[19], x0, g[18]), x0, g[17]), x0, g[16]), x0, g[15]);
    float s1 = fmaf(fmaf(fmaf(g[23], x0, g[22]), x0, g[21]), x0, g[20]);
    float s2 = fmaf(fmaf(g[26], x0, g[25]), x0, g[24]);
    float s3 = fmaf(g[28], x0, g[27]);
    float s4 = g[29];
    d1 = fmaf(fmaf(fmaf(fmaf(s4, x1, s3), x1, s2), x1, s1), x1, s0);
}

__global__ void __launch_bounds__(256) sympl_fused(const float* __restrict__ zin,
                                                   const float* __restrict__ Aw,
                                                   const float* __restrict__ Bw,
                                                   const float* __restrict__ Cw,
                                                   const float* __restrict__ Dw,
                                                   const int* __restrict__ nsp,
                                                   float* __restrict__ zout, int batch) {
    __shared__ float sG[NSTEP * 128];

    int lt = threadIdx.x;

    // ---- per-block redundant prep: 128 (step, stage) collapse tasks ----
    if (lt < NSTEP * 4) {
        int stepi = lt >> 2, which = lt & 3;
        const float* w;
        switch (which) { case 0: w = Aw; break; case 1: w = Bw; break;
                         case 2: w = Cw; break; default: w = Dw; }
        w += stepi * 62;

        float c[6][6];
#pragma unroll
        for (int a = 0; a < 6; ++a)
#pragma unroll
            for (int b = 0; b < 6; ++b) c[a][b] = 0.f;

        // degree-d flat index f: bits of f are the 62-monomial indices;
        // popcount(f) = power of x1
#pragma unroll
        for (int d = 1; d <= 5; ++d) {
#pragma unroll
            for (int f = 0; f < (1 << d); ++f) {
                int b = __popc(f);
                c[d - b][b] += w[(1 << d) - 2 + f];
            }
        }

        float* dst = sG + lt * 32;
        int k = 0;
#pragma unroll
        for (int e0 = 0; e0 <= 4; ++e0)
#pragma unroll
            for (int e1 = 0; e1 + e0 <= 4; ++e1)
                dst[k++] = (float)(e0 + 1) * c[e0 + 1][e1];
#pragma unroll
        for (int e1 = 0; e1 <= 4; ++e1)
#pragma unroll
            for (int e0 = 0; e0 + e1 <= 4; ++e0)
                dst[k++] = (float)(e1 + 1) * c[e0][e1 + 1];
        dst[30] = 0.f; dst[31] = 0.f;
    }
    __syncthreads();

    // ---- main integration ----
    int idx = blockIdx.x * 256 + lt;
    bool active = idx < batch;
    float dt  = 1.0f / (32.0f * (float)nsp[0]);
    float hdt = 0.5f * dt;

    float4 zv = make_float4(0.f, 0.f, 0.f, 0.f);
    if (active) zv = reinterpret_cast<const float4*>(zin)[idx];
    float q0 = zv.x, q1 = zv.y, p0 = zv.z, p1 = zv.w;

    // stage-ahead register double-buffer: while stage k computes, stage k+1's
    // 32 floats are in flight from LDS (uniform-address broadcast reads).
    float bufA[32], bufB[32];
    loadstage(sG, bufA);                                   // step 0, stage A

    for (int s = 0; s < NSTEP; ++s) {
        const float* gS = sG + s * 128;
        int sn = (s + 1 < NSTEP) ? s + 1 : NSTEP - 1;

        loadstage(gS + 32, bufB);                          // B coefs in flight
        float dA0, dA1; pgrad(bufA, p0, p1, dA0, dA1);
        q0 = fmaf(dA0, hdt, q0); q1 = fmaf(dA1, hdt, q1);

        loadstage(gS + 64, bufA);                          // C coefs in flight
        float dB0, dB1; pgrad(bufB, q0, q1, dB0, dB1);
        p0 = fmaf(-dB0, dt, p0); p1 = fmaf(-dB1, dt, p1);
        q0 = fmaf(dA0, hdt, q0); q1 = fmaf(dA1, hdt, q1);

        float u0 = q1, u1 = p0, v0 = q0, v1 = p1;

        loadstage(gS + 96, bufB);                          // D coefs in flight
        float dC0, dC1; pgrad(bufA, v0, v1, dC0, dC1);
        u0 = fmaf(dC1, hdt, u0); u1 = fmaf(-dC0, hdt, u1);

        loadstage(sG + sn * 128, bufA);                    // next step A coefs
        float dD0, dD1; pgrad(bufB, u0, u1, dD0, dD1);
        v0 = fmaf(dD1, dt, v0); v1 = fmaf(-dD0, dt, v1);
        u0 = fmaf(dC1, hdt, u0); u1 = fmaf(-dC0, hdt, u1);

        q0 = v0; q1 = u0; p0 = u1; p1 = v1;                // z = [v0, u0, u1, v1]
    }

    if (active) {
        float4 o; o.x = q0; o.y = q1; o.z = p0; o.w = p1;
        reinterpret_cast<float4*>(zout)[idx] = o;
    }
}

extern "C" void kernel_launch(void* const* d_in, const int* in_sizes, int n_in,
                              void* d_out, int out_size, void* d_ws, size_t ws_size,
                              hipStream_t stream) {
    const float* z  = (const float*)d_in[0];
    const float* Aw = (const float*)d_in[1];
    const float* Bw = (const float*)d_in[2];
    const float* Cw = (const float*)d_in[3];
    const float* Dw = (const float*)d_in[4];
    const int*   ns = (const int*)d_in[5];

    int batch = in_sizes[0] / 4;
    int threads = 256;
    int blocks = (batch + threads - 1) / threads;
    sympl_fused<<<blocks, threads, 0, stream>>>(z, Aw, Bw, Cw, Dw, ns,
                                                (float*)d_out, batch);
}

// Round 3
// 20.631 us; speedup vs baseline: 1.8813x; 1.0078x over previous
//
#include <hip/hip_runtime.h>

#define NSTEP 32
// DIM = 62 monomials of degree 1..5 over (x0,x1); collapsed to 30 gradient
// coefficients per (step, stage). LDS layout (tightly packed):
//   sG[step*120 + stage*30 + k]
// k=0..14  -> dP/dx0 coeffs (triangular rows by e0, widths 5,4,3,2,1; inner Horner in x1)
// k=15..29 -> dP/dx1 coeffs (rows by e1; inner Horner in x0)
// 120 floats/step = 480 B (16B-aligned) -> 30 ds_read_b128 per step.

__device__ __forceinline__ void loadstep(const float* __restrict__ sg, float (&R)[120]) {
#pragma unroll
    for (int i = 0; i < 30; ++i) {
        float4 v = *reinterpret_cast<const float4*>(sg + i * 4);
        R[i * 4 + 0] = v.x; R[i * 4 + 1] = v.y;
        R[i * 4 + 2] = v.z; R[i * 4 + 3] = v.w;
    }
}

template <int B>
__device__ __forceinline__ void pgrad(const float (&g)[120], float x0, float x1,
                                      float& d0, float& d1) {
    float r0 = fmaf(fmaf(fmaf(fmaf(g[B+4], x1, g[B+3]), x1, g[B+2]), x1, g[B+1]), x1, g[B+0]);
    float r1 = fmaf(fmaf(fmaf(g[B+8], x1, g[B+7]), x1, g[B+6]), x1, g[B+5]);
    float r2 = fmaf(fmaf(g[B+11], x1, g[B+10]), x1, g[B+9]);
    float r3 = fmaf(g[B+13], x1, g[B+12]);
    float r4 = g[B+14];
    d0 = fmaf(fmaf(fmaf(fmaf(r4, x0, r3), x0, r2), x0, r1), x0, r0);

    float s0 = fmaf(fmaf(fmaf(fmaf(g[B+19], x0, g[B+18]), x0, g[B+17]), x0, g[B+16]), x0, g[B+15]);
    float s1 = fmaf(fmaf(fmaf(g[B+23], x0, g[B+22]), x0, g[B+21]), x0, g[B+20]);
    float s2 = fmaf(fmaf(g[B+26], x0, g[B+25]), x0, g[B+24]);
    float s3 = fmaf(g[B+28], x0, g[B+27]);
    float s4 = g[B+29];
    d1 = fmaf(fmaf(fmaf(fmaf(s4, x1, s3), x1, s2), x1, s1), x1, s0);
}

__device__ __forceinline__ void dostep(const float (&g)[120], float& q0, float& q1,
                                       float& p0, float& p1, float dt, float hdt) {
    float dA0, dA1; pgrad<0>(g, p0, p1, dA0, dA1);
    q0 = fmaf(dA0, hdt, q0); q1 = fmaf(dA1, hdt, q1);

    float dB0, dB1; pgrad<30>(g, q0, q1, dB0, dB1);
    p0 = fmaf(-dB0, dt, p0); p1 = fmaf(-dB1, dt, p1);
    q0 = fmaf(dA0, hdt, q0); q1 = fmaf(dA1, hdt, q1);

    float u0 = q1, u1 = p0, v0 = q0, v1 = p1;

    float dC0, dC1; pgrad<60>(g, v0, v1, dC0, dC1);
    u0 = fmaf(dC1, hdt, u0); u1 = fmaf(-dC0, hdt, u1);

    float dD0, dD1; pgrad<90>(g, u0, u1, dD0, dD1);
    v0 = fmaf(dD1, dt, v0); v1 = fmaf(-dD0, dt, v1);
    u0 = fmaf(dC1, hdt, u0); u1 = fmaf(-dC0, hdt, u1);

    q0 = v0; q1 = u0; p0 = u1; p1 = v1;   // z = [v0, u0, u1, v1]
}

__global__ void __launch_bounds__(256, 1)
sympl_fused(const float* __restrict__ zin,
            const float* __restrict__ Aw, const float* __restrict__ Bw,
            const float* __restrict__ Cw, const float* __restrict__ Dw,
            const int* __restrict__ nsp,
            float* __restrict__ zout, int batch) {
    __shared__ float sG[NSTEP * 120];

    int lt = threadIdx.x;
    int idx = blockIdx.x * 256 + lt;
    bool active = idx < batch;

    // issue the z load immediately (independent of prep)
    float4 zv = make_float4(0.f, 0.f, 0.f, 0.f);
    if (active) zv = reinterpret_cast<const float4*>(zin)[idx];
    float dt  = 1.0f / (32.0f * (float)nsp[0]);
    float hdt = 0.5f * dt;

    // ---- per-block redundant prep: 128 (step, stage) collapse tasks ----
    if (lt < NSTEP * 4) {
        int stepi = lt >> 2, which = lt & 3;
        const float* w;
        switch (which) { case 0: w = Aw; break; case 1: w = Bw; break;
                         case 2: w = Cw; break; default: w = Dw; }
        w += stepi * 62;

        float c[6][6];
#pragma unroll
        for (int a = 0; a < 6; ++a)
#pragma unroll
            for (int b = 0; b < 6; ++b) c[a][b] = 0.f;

        // degree-d flat index f: bits of f are the monomial indices;
        // popcount(f) = power of x1
#pragma unroll
        for (int d = 1; d <= 5; ++d) {
#pragma unroll
            for (int f = 0; f < (1 << d); ++f) {
                int b = __popc(f);
                c[d - b][b] += w[(1 << d) - 2 + f];
            }
        }

        float* dst = sG + stepi * 120 + which * 30;
        int k = 0;
#pragma unroll
        for (int e0 = 0; e0 <= 4; ++e0)
#pragma unroll
            for (int e1 = 0; e1 + e0 <= 4; ++e1)
                dst[k++] = (float)(e0 + 1) * c[e0 + 1][e1];
#pragma unroll
        for (int e1 = 0; e1 <= 4; ++e1)
#pragma unroll
            for (int e0 = 0; e0 + e1 <= 4; ++e0)
                dst[k++] = (float)(e1 + 1) * c[e0][e1 + 1];
    }
    __syncthreads();

    float q0 = zv.x, q1 = zv.y, p0 = zv.z, p1 = zv.w;

    // ---- main loop: full-step register double buffer, unroll x2 ----
    float bufX[120], bufY[120];
    loadstep(sG, bufX);                       // step 0

#pragma unroll 1
    for (int it = 0; it < NSTEP / 2; ++it) {
        int s = 2 * it;
        // step s: compute from X, prefetch step s+1 into Y
        loadstep(sG + (s + 1) * 120, bufY);
        dostep(bufX, q0, q1, p0, p1, dt, hdt);
        // step s+1: compute from Y, prefetch step s+2 into X
        int sn = (s + 2 < NSTEP) ? s + 2 : NSTEP - 1;
        loadstep(sG + sn * 120, bufX);
        dostep(bufY, q0, q1, p0, p1, dt, hdt);
    }

    if (active) {
        float4 o; o.x = q0; o.y = q1; o.z = p0; o.w = p1;
        reinterpret_cast<float4*>(zout)[idx] = o;
    }
}

extern "C" void kernel_launch(void* const* d_in, const int* in_sizes, int n_in,
                              void* d_out, int out_size, void* d_ws, size_t ws_size,
                              hipStream_t stream) {
    const float* z  = (const float*)d_in[0];
    const float* Aw = (const float*)d_in[1];
    const float* Bw = (const float*)d_in[2];
    const float* Cw = (const float*)d_in[3];
    const float* Dw = (const float*)d_in[4];
    const int*   ns = (const int*)d_in[5];

    int batch = in_sizes[0] / 4;
    int threads = 256;
    int blocks = (batch + threads - 1) / threads;
    sympl_fused<<<blocks, threads, 0, stream>>>(z, Aw, Bw, Cw, Dw, ns,
                                                (float*)d_out, batch);
}